// Round 4
// baseline (121.564 us; speedup 1.0000x reference)
//
#include <hip/hip_runtime.h>
#include <hip/hip_bf16.h>

#define MARGIN 0.0625f

// Problem sizes (fixed by the reference)
#define B 64
#define N 64
#define P 4096        // B*N query points
#define M 100000      // means
#define G 500         // mean-chunks: 500*200 = 100000 exactly (no padding!)
#define CHUNK 200
#define QS 2          // query slabs (grid = G*QS = 1000 blocks)
#define R 8           // queries per thread (256*R*QS = 4096)
#define NB 4          // float2 bundles = R/2
#define GRP 8         // means per software-pipeline group
#define NIT (CHUNK / GRP)   // 25
#define SEG 4         // g-segments in reduce kernel
#define GPERSEG (G / SEG)   // 125

typedef float float2v __attribute__((ext_vector_type(2)));

// ws layout: partial[G*P] floats = 500*4096*4 = 8,192,000 bytes
// d_out is zeroed by nn_kernel (block (0,0), thread 0); reduce_kernel
// atomicAdds into it (separate dispatch -> stream-ordered, safe).

// ---------------------------------------------------------------------------
// Kernel 1: fused query-transform + NN scan.
// Grid (G, QS). Block (g,qs): means [g*CHUNK,(g+1)*CHUNK) vs 2048 queries of
// slab qs. Thread holds R=8 queries as 4 float2 bundles (packed fp32 math).
// Means are read with wave-uniform loads (scalarize to s_load), 8 per group,
// double-buffered. d' = mm - 2 q.m accumulated (seeded by mm, no add);
// qq folded in at the epilogue.
// ---------------------------------------------------------------------------
__global__ __launch_bounds__(256) void nn_kernel(
    const float* __restrict__ outputs,   // [B*N*3]
    const float* __restrict__ c2ws,      // [B*16]
    const float* __restrict__ scales,    // [B]
    const float* __restrict__ means,     // [M*3]
    float* __restrict__ partial,         // [G*P]
    float* __restrict__ out)
{
    const int t  = threadIdx.x;
    const int g  = blockIdx.x;
    const int qs = blockIdx.y;
    if (g == 0 && qs == 0 && t == 0) out[0] = 0.0f;   // for reduce's atomicAdd

    const int pbase = qs * (P / QS);

    // ---- compute my 8 queries inline (b = p>>6 is wave-uniform) ----
    float2v qxn[NB], qyn[NB], qzn[NB], mn[NB];
    float qq[R];
#pragma unroll
    for (int i = 0; i < R; ++i) {
        int p = pbase + i * 256 + t;
        int b = p >> 6;
        float s  = scales[b];
        float o0 = outputs[3 * p + 0];
        float o1 = outputs[3 * p + 1];
        float o2 = outputs[3 * p + 2];
        const float* cw = c2ws + b * 16;
        float q0 = fmaf(s, fmaf(cw[0],  o0, fmaf(cw[1],  o1, cw[2]  * o2)), cw[3]);
        float q1 = fmaf(s, fmaf(cw[4],  o0, fmaf(cw[5],  o1, cw[6]  * o2)), cw[7]);
        float q2 = fmaf(s, fmaf(cw[8],  o0, fmaf(cw[9],  o1, cw[10] * o2)), cw[11]);
        qq[i] = fmaf(q0, q0, fmaf(q1, q1, q2 * q2));
        qxn[i >> 1][i & 1] = -2.0f * q0;
        qyn[i >> 1][i & 1] = -2.0f * q1;
        qzn[i >> 1][i & 1] = -2.0f * q2;
        mn [i >> 1][i & 1] = 1e30f;
    }

    // ---- scan means: 8 per group, double-buffered uniform loads ----
    const float* mp = means + 3 * g * CHUNK;
    float cur[3 * GRP], nxt[3 * GRP];
#pragma unroll
    for (int c = 0; c < 3 * GRP; ++c) cur[c] = mp[c];

    for (int it = 0; it < NIT; ++it) {
        const float* nx = mp + 3 * GRP * (it + 1);
        if (it < NIT - 1) {
#pragma unroll
            for (int c = 0; c < 3 * GRP; ++c) nxt[c] = nx[c];
        }
#pragma unroll
        for (int j = 0; j < GRP; j += 2) {
            float x0 = cur[3 * j + 0], y0 = cur[3 * j + 1], z0 = cur[3 * j + 2];
            float x1 = cur[3 * j + 3], y1 = cur[3 * j + 4], z1 = cur[3 * j + 5];
            float mm0 = fmaf(x0, x0, fmaf(y0, y0, z0 * z0));
            float mm1 = fmaf(x1, x1, fmaf(y1, y1, z1 * z1));
            float2v vx0 = {x0, x0}, vy0 = {y0, y0}, vz0 = {z0, z0}, vm0 = {mm0, mm0};
            float2v vx1 = {x1, x1}, vy1 = {y1, y1}, vz1 = {z1, z1}, vm1 = {mm1, mm1};
#pragma unroll
            for (int u = 0; u < NB; ++u) {
                float2v d0 = __builtin_elementwise_fma(qxn[u], vx0,
                             __builtin_elementwise_fma(qyn[u], vy0,
                             __builtin_elementwise_fma(qzn[u], vz0, vm0)));
                float2v d1 = __builtin_elementwise_fma(qxn[u], vx1,
                             __builtin_elementwise_fma(qyn[u], vy1,
                             __builtin_elementwise_fma(qzn[u], vz1, vm1)));
                mn[u] = __builtin_elementwise_min(mn[u],
                        __builtin_elementwise_min(d0, d1));
            }
        }
        if (it < NIT - 1) {
#pragma unroll
            for (int c = 0; c < 3 * GRP; ++c) cur[c] = nxt[c];
        }
    }

    // ---- epilogue: clamped d2 (>= 0), coalesced store ----
#pragma unroll
    for (int i = 0; i < R; ++i) {
        int p = pbase + i * 256 + t;
        partial[g * P + p] = fmaxf(qq[i] + mn[i >> 1][i & 1], 0.0f);
    }
}

// ---------------------------------------------------------------------------
// Kernel 2: fused reduction. 64 blocks x 256 threads. Block owns 64 queries;
// wave w scans g-segment [w*125,(w+1)*125) for all 64 (coalesced 256B reads),
// LDS min-combine across the 4 segments, relu(MARGIN-d)/P, wave-sum,
// atomicAdd into out.
// ---------------------------------------------------------------------------
__global__ __launch_bounds__(256) void reduce_kernel(
    const float* __restrict__ partial,
    float* __restrict__ out)
{
    const int t = threadIdx.x;
    const int w = t >> 6;          // segment
    const int l = t & 63;          // query lane
    const int p = blockIdx.x * 64 + l;

    float m = 1e30f;
#pragma unroll 5
    for (int gi = 0; gi < GPERSEG; ++gi)
        m = fminf(m, partial[(w * GPERSEG + gi) * P + p]);

    __shared__ float lds[SEG][64];
    lds[w][l] = m;
    __syncthreads();

    if (t < 64) {
        m = fminf(fminf(lds[0][l], lds[1][l]), fminf(lds[2][l], lds[3][l]));
        float v = fmaxf(MARGIN - m, 0.0f) * (1.0f / (float)P);
#pragma unroll
        for (int off = 32; off > 0; off >>= 1)
            v += __shfl_down(v, off, 64);
        if (l == 0)
            atomicAdd(out, v);
    }
}

extern "C" void kernel_launch(void* const* d_in, const int* in_sizes, int n_in,
                              void* d_out, int out_size, void* d_ws, size_t ws_size,
                              hipStream_t stream) {
    const float* outputs = (const float*)d_in[0];  // (64,64,3)
    const float* c2ws    = (const float*)d_in[1];  // (64,4,4)
    const float* scales  = (const float*)d_in[2];  // (64,)
    const float* means   = (const float*)d_in[3];  // (100000,3)

    float* partial = (float*)d_ws;                 // 8.192 MB
    float* out     = (float*)d_out;

    nn_kernel<<<dim3(G, QS), 256, 0, stream>>>(outputs, c2ws, scales, means,
                                               partial, out);
    reduce_kernel<<<64, 256, 0, stream>>>(partial, out);
}

// Round 5
// 106.404 us; speedup vs baseline: 1.1425x; 1.1425x over previous
//
#include <hip/hip_runtime.h>
#include <hip/hip_bf16.h>

#define MARGIN 0.0625f

// Problem sizes (fixed by the reference)
#define P 4096        // 64*64 query points
#define M 100000      // means
#define G 500         // mean-chunks: 500*200 = 100000 exactly
#define CHUNK 200
#define QS 2          // query slabs (grid = G*QS = 1000 blocks)
#define R 8           // queries per thread (256*R*QS = 4096)
#define GRP 8         // means per software-pipeline group (4 pair-slots)
#define NITG (CHUNK / GRP)   // 25

typedef float float2v __attribute__((ext_vector_type(2)));

// ws layout (floats):
//   xs[M] @ 0, ys[M] @ 400000B, zs[M] @ 800000B, ms[M] @ 1200000B  (SoA -2x,-2y,-2z,|m|^2)
//   partial[G*P] @ 1600000B  (8,192,000 B)  -> total 9,792,000 B
#define WS_XS_OFF      0
#define WS_YS_OFF      400000
#define WS_ZS_OFF      800000
#define WS_MS_OFF      1200000
#define WS_PARTIAL_OFF 1600000

// ---------------------------------------------------------------------------
// Kernel 1: means -> SoA pack (-2x, -2y, -2z, |m|^2); zero out[0].
// Consecutive pairs (xs[2k], xs[2k+1]) become even-aligned SGPR pairs in nn,
// i.e. direct VOP3P operands with no splat movs.
// ---------------------------------------------------------------------------
__global__ __launch_bounds__(256) void prep_kernel(
    const float* __restrict__ means,
    float* __restrict__ xs, float* __restrict__ ys,
    float* __restrict__ zs, float* __restrict__ ms,
    float* __restrict__ out)
{
    int idx = blockIdx.x * 256 + threadIdx.x;
    if (idx == 0) out[0] = 0.0f;   // reduce atomicAdds later (stream-ordered)
    if (idx < M) {
        float x = means[3 * idx + 0];
        float y = means[3 * idx + 1];
        float z = means[3 * idx + 2];
        xs[idx] = -2.0f * x;
        ys[idx] = -2.0f * y;
        zs[idx] = -2.0f * z;
        ms[idx] = fmaf(x, x, fmaf(y, y, z * z));
    }
}

// ---------------------------------------------------------------------------
// Kernel 2: fused query-transform + NN scan, mean-pair-packed fp32.
// Grid (G, QS) = 1000 blocks. Block (g,qs): means [g*CHUNK,(g+1)*CHUNK) vs
// 2048 queries of slab qs; thread holds R=8 queries. Query components are
// splat into VGPR pairs ONCE; mean pairs arrive as SGPR pairs via uniform
// s_loads (software-pipelined one 8-mean group ahead). Inner op per
// 2-means x query: 3 v_pk_fma_f32 + 1 v_pk_min_f32, zero splat movs.
// ---------------------------------------------------------------------------
__global__ __launch_bounds__(256, 4) void nn_kernel(
    const float* __restrict__ outputs,   // [P*3]
    const float* __restrict__ c2ws,      // [64*16]
    const float* __restrict__ scales,    // [64]
    const float* __restrict__ xs, const float* __restrict__ ys,
    const float* __restrict__ zs, const float* __restrict__ ms,
    float* __restrict__ partial)         // [G*P]
{
    const int t  = threadIdx.x;
    const int g  = blockIdx.x;
    const int qs = blockIdx.y;
    const int pbase = qs * (P / QS);
    const int mbase = g * CHUNK;

    // ---- queries: compute inline, splat to VGPR pairs once ----
    float2v qxs[R], qys[R], qzs[R], mn[R];
    float qq[R];
#pragma unroll
    for (int i = 0; i < R; ++i) {
        int p = pbase + i * 256 + t;
        int b = p >> 6;
        float s  = scales[b];
        float o0 = outputs[3 * p + 0];
        float o1 = outputs[3 * p + 1];
        float o2 = outputs[3 * p + 2];
        const float* cw = c2ws + b * 16;
        float q0 = fmaf(s, fmaf(cw[0],  o0, fmaf(cw[1],  o1, cw[2]  * o2)), cw[3]);
        float q1 = fmaf(s, fmaf(cw[4],  o0, fmaf(cw[5],  o1, cw[6]  * o2)), cw[7]);
        float q2 = fmaf(s, fmaf(cw[8],  o0, fmaf(cw[9],  o1, cw[10] * o2)), cw[11]);
        qq[i] = fmaf(q0, q0, fmaf(q1, q1, q2 * q2));
        qxs[i] = (float2v){q0, q0};
        qys[i] = (float2v){q1, q1};
        qzs[i] = (float2v){q2, q2};
        mn[i]  = (float2v){1e30f, 1e30f};
    }

#define LD2(arr, off) (*(const float2v*)((arr) + mbase + (off)))

    // preload first group (4 pair-slots = 8 means); uniform -> s_loads
    float2v cx[4], cy[4], cz[4], cm[4];
#pragma unroll
    for (int s = 0; s < 4; ++s) {
        cx[s] = LD2(xs, 2 * s); cy[s] = LD2(ys, 2 * s);
        cz[s] = LD2(zs, 2 * s); cm[s] = LD2(ms, 2 * s);
    }

    for (int kg = 0; kg < NITG; ++kg) {
        float2v nx[4], ny[4], nz[4], nm[4];
        if (kg < NITG - 1) {
            int nb = (kg + 1) * GRP;
#pragma unroll
            for (int s = 0; s < 4; ++s) {
                nx[s] = LD2(xs, nb + 2 * s); ny[s] = LD2(ys, nb + 2 * s);
                nz[s] = LD2(zs, nb + 2 * s); nm[s] = LD2(ms, nb + 2 * s);
            }
        }
#pragma unroll
        for (int s = 0; s < 4; ++s) {
#pragma unroll
            for (int i = 0; i < R; ++i) {
                // d'(pair) = mm + (-2x)*qx + (-2y)*qy + (-2z)*qz
                float2v d = __builtin_elementwise_fma(qzs[i], cz[s],
                            __builtin_elementwise_fma(qys[i], cy[s],
                            __builtin_elementwise_fma(qxs[i], cx[s], cm[s])));
                mn[i] = __builtin_elementwise_min(mn[i], d);
            }
        }
        if (kg < NITG - 1) {
#pragma unroll
            for (int s = 0; s < 4; ++s) {
                cx[s] = nx[s]; cy[s] = ny[s]; cz[s] = nz[s]; cm[s] = nm[s];
            }
        }
    }
#undef LD2

    // ---- epilogue: fold pair, add qq, clamp, coalesced store ----
#pragma unroll
    for (int i = 0; i < R; ++i) {
        int p = pbase + i * 256 + t;
        float m = fminf(mn[i][0], mn[i][1]);
        partial[g * P + p] = fmaxf(qq[i] + m, 0.0f);
    }
}

// ---------------------------------------------------------------------------
// Kernel 3: reduction. 256 blocks x 256 threads. Block owns 16 queries;
// thread (seg = t>>4, qi = t&15) scans g in [seg*32, min(seg*32+32, 500)),
// 32 independent loads. LDS 16x16 combine, relu(MARGIN-d)/P, wave-0 sum,
// atomicAdd into out.
// ---------------------------------------------------------------------------
__global__ __launch_bounds__(256) void reduce_kernel(
    const float* __restrict__ partial,
    float* __restrict__ out)
{
    const int t   = threadIdx.x;
    const int qi  = t & 15;
    const int seg = t >> 4;
    const int q   = blockIdx.x * 16 + qi;

    float m = 1e30f;
    const int gbeg = seg * 32;
    const int gend = (gbeg + 32 < G) ? gbeg + 32 : G;
    for (int g = gbeg; g < gend; ++g)
        m = fminf(m, partial[g * P + q]);

    __shared__ float sm[16][16];
    sm[seg][qi] = m;
    __syncthreads();

    float v = 0.0f;
    if (t < 16) {
        float mm = sm[0][t];
#pragma unroll
        for (int s = 1; s < 16; ++s)
            mm = fminf(mm, sm[s][t]);
        v = fmaxf(MARGIN - mm, 0.0f) * (1.0f / (float)P);
    }
    if (t < 64) {
#pragma unroll
        for (int off = 32; off > 0; off >>= 1)
            v += __shfl_down(v, off, 64);
        if (t == 0)
            atomicAdd(out, v);
    }
}

extern "C" void kernel_launch(void* const* d_in, const int* in_sizes, int n_in,
                              void* d_out, int out_size, void* d_ws, size_t ws_size,
                              hipStream_t stream) {
    const float* outputs = (const float*)d_in[0];  // (64,64,3)
    const float* c2ws    = (const float*)d_in[1];  // (64,4,4)
    const float* scales  = (const float*)d_in[2];  // (64,)
    const float* means   = (const float*)d_in[3];  // (100000,3)

    char* ws = (char*)d_ws;
    float* xs      = (float*)(ws + WS_XS_OFF);
    float* ys      = (float*)(ws + WS_YS_OFF);
    float* zs      = (float*)(ws + WS_ZS_OFF);
    float* ms      = (float*)(ws + WS_MS_OFF);
    float* partial = (float*)(ws + WS_PARTIAL_OFF);
    float* out     = (float*)d_out;

    prep_kernel<<<(M + 255) / 256, 256, 0, stream>>>(means, xs, ys, zs, ms, out);
    nn_kernel<<<dim3(G, QS), 256, 0, stream>>>(outputs, c2ws, scales,
                                               xs, ys, zs, ms, partial);
    reduce_kernel<<<256, 256, 0, stream>>>(partial, out);
}

// Round 6
// 105.522 us; speedup vs baseline: 1.1520x; 1.0084x over previous
//
#include <hip/hip_runtime.h>
#include <hip/hip_bf16.h>

#define MARGIN 0.0625f

// Problem sizes (fixed by the reference)
#define P 4096        // 64*64 query points
#define M 100000      // means
#define G 500         // mean-chunks: 500*200 = 100000 exactly
#define CHUNK 200     // means per block  (100 pairs)
#define NPAIR (CHUNK / 2)
#define QS 2          // query slabs (grid = G*QS = 1000 blocks)
#define R 8           // queries per thread (256*R*QS = 4096)
#define HSEG 16       // g-segments in reduce1

typedef float float2v __attribute__((ext_vector_type(2)));

// ws layout (bytes):
//   xs[M] @ 0, ys[M] @ 400000, zs[M] @ 800000, ms[M] @ 1200000   (SoA -2x,-2y,-2z,|m|^2... actually x,y,z as-is? see prep)
//   partial [G*P]  @ 1600000   (8,192,000)
//   partial2[HSEG*P] @ 9792000 (262,144)       total ~10.05 MB
#define WS_XS_OFF      0
#define WS_YS_OFF      400000
#define WS_ZS_OFF      800000
#define WS_MS_OFF      1200000
#define WS_PARTIAL_OFF 1600000
#define WS_PART2_OFF   9792000

// ---------------------------------------------------------------------------
// Kernel 1: means -> SoA (-2x, -2y, -2z, |m|^2); zero out[0].
// ---------------------------------------------------------------------------
__global__ __launch_bounds__(256) void prep_kernel(
    const float* __restrict__ means,
    float* __restrict__ xs, float* __restrict__ ys,
    float* __restrict__ zs, float* __restrict__ ms,
    float* __restrict__ out)
{
    int idx = blockIdx.x * 256 + threadIdx.x;
    if (idx == 0) out[0] = 0.0f;   // reduce2 atomicAdds later (stream-ordered)
    if (idx < M) {
        float x = means[3 * idx + 0];
        float y = means[3 * idx + 1];
        float z = means[3 * idx + 2];
        xs[idx] = -2.0f * x;
        ys[idx] = -2.0f * y;
        zs[idx] = -2.0f * z;
        ms[idx] = fmaf(x, x, fmaf(y, y, z * z));
    }
}

// ---------------------------------------------------------------------------
// Kernel 2: fused query-transform + NN scan, LDS-staged mean pairs.
// Grid (G, QS) = 1000 blocks. Block (g,qs): stages its 200-mean chunk into
// LDS (3.2 KB, float2 pairs), then every wave reads pairs at wave-uniform
// LDS addresses (broadcast, conflict-free, LDS pipe) and does
// 3 v_pk_fma_f32 + 1 v_pk_min_f32 per 2 means per query. All VALU operands
// are VGPRs -- no reliance on compiler scalarization of global loads.
// ---------------------------------------------------------------------------
__global__ __launch_bounds__(256, 4) void nn_kernel(
    const float* __restrict__ outputs,   // [P*3]
    const float* __restrict__ c2ws,      // [64*16]
    const float* __restrict__ scales,    // [64]
    const float* __restrict__ xs, const float* __restrict__ ys,
    const float* __restrict__ zs, const float* __restrict__ ms,
    float* __restrict__ partial)         // [G*P]
{
    const int t  = threadIdx.x;
    const int g  = blockIdx.x;
    const int qs = blockIdx.y;
    const int pbase = qs * (P / QS);
    const int mbase = g * CHUNK;

    __shared__ float2v lxs[NPAIR], lys[NPAIR], lzs[NPAIR], lms[NPAIR];

    // ---- stage mean chunk into LDS (coalesced dwordx2 loads) ----
    if (t < NPAIR) {
        lxs[t] = *(const float2v*)(xs + mbase + 2 * t);
        lys[t] = *(const float2v*)(ys + mbase + 2 * t);
        lzs[t] = *(const float2v*)(zs + mbase + 2 * t);
        lms[t] = *(const float2v*)(ms + mbase + 2 * t);
    }

    // ---- queries: compute inline, splat to VGPR pairs once ----
    float2v qxs[R], qys[R], qzs[R], mn[R];
    float qq[R];
#pragma unroll
    for (int i = 0; i < R; ++i) {
        int p = pbase + i * 256 + t;
        int b = p >> 6;
        float s  = scales[b];
        float o0 = outputs[3 * p + 0];
        float o1 = outputs[3 * p + 1];
        float o2 = outputs[3 * p + 2];
        const float* cw = c2ws + b * 16;
        float q0 = fmaf(s, fmaf(cw[0],  o0, fmaf(cw[1],  o1, cw[2]  * o2)), cw[3]);
        float q1 = fmaf(s, fmaf(cw[4],  o0, fmaf(cw[5],  o1, cw[6]  * o2)), cw[7]);
        float q2 = fmaf(s, fmaf(cw[8],  o0, fmaf(cw[9],  o1, cw[10] * o2)), cw[11]);
        qq[i] = fmaf(q0, q0, fmaf(q1, q1, q2 * q2));
        qxs[i] = (float2v){q0, q0};
        qys[i] = (float2v){q1, q1};
        qzs[i] = (float2v){q2, q2};
        mn[i]  = (float2v){1e30f, 1e30f};
    }

    __syncthreads();

    // ---- scan 100 mean-pairs from LDS ----
#pragma unroll 4
    for (int j = 0; j < NPAIR; ++j) {
        float2v cx = lxs[j];   // wave-uniform address -> LDS broadcast
        float2v cy = lys[j];
        float2v cz = lzs[j];
        float2v cm = lms[j];
#pragma unroll
        for (int i = 0; i < R; ++i) {
            // d'(pair) = mm + (-2x)*qx + (-2y)*qy + (-2z)*qz
            float2v d = __builtin_elementwise_fma(qzs[i], cz,
                        __builtin_elementwise_fma(qys[i], cy,
                        __builtin_elementwise_fma(qxs[i], cx, cm)));
            mn[i] = __builtin_elementwise_min(mn[i], d);
        }
    }

    // ---- epilogue: fold pair, add qq, clamp, coalesced store ----
#pragma unroll
    for (int i = 0; i < R; ++i) {
        int p = pbase + i * 256 + t;
        float m = fminf(mn[i][0], mn[i][1]);
        partial[g * P + p] = fmaxf(qq[i] + m, 0.0f);
    }
}

// ---------------------------------------------------------------------------
// Kernel 3: stage-1 min. Grid (16 q-slabs, 16 g-segments of 32 (last 20)).
// Block (s,h): 256 consecutive queries (coalesced), min over its g range.
// ---------------------------------------------------------------------------
__global__ __launch_bounds__(256) void reduce1_kernel(
    const float* __restrict__ partial,
    float* __restrict__ partial2)        // [HSEG*P]
{
    const int t = threadIdx.x;
    const int s = blockIdx.x;
    const int h = blockIdx.y;
    const int q = s * 256 + t;

    const int gbeg = h * 32;
    const int gend = (gbeg + 32 < G) ? gbeg + 32 : G;

    float m = 1e30f;
#pragma unroll 4
    for (int g = gbeg; g < gend; ++g)
        m = fminf(m, partial[g * P + q]);

    partial2[h * P + q] = m;
}

// ---------------------------------------------------------------------------
// Kernel 4: stage-2 min over HSEG=16 (256 KB, L2-hot), relu(MARGIN-d)/P,
// block-sum, atomicAdd into out.
// ---------------------------------------------------------------------------
__global__ __launch_bounds__(256) void reduce2_kernel(
    const float* __restrict__ partial2,
    float* __restrict__ out)
{
    const int t = threadIdx.x;
    const int q = blockIdx.x * 256 + t;

    float m = 1e30f;
#pragma unroll
    for (int h = 0; h < HSEG; ++h)
        m = fminf(m, partial2[h * P + q]);

    float v = fmaxf(MARGIN - m, 0.0f) * (1.0f / (float)P);

#pragma unroll
    for (int off = 32; off > 0; off >>= 1)
        v += __shfl_down(v, off, 64);

    __shared__ float lds[4];
    int wid = t >> 6;
    if ((t & 63) == 0) lds[wid] = v;
    __syncthreads();
    if (t == 0)
        atomicAdd(out, lds[0] + lds[1] + lds[2] + lds[3]);
}

extern "C" void kernel_launch(void* const* d_in, const int* in_sizes, int n_in,
                              void* d_out, int out_size, void* d_ws, size_t ws_size,
                              hipStream_t stream) {
    const float* outputs = (const float*)d_in[0];  // (64,64,3)
    const float* c2ws    = (const float*)d_in[1];  // (64,4,4)
    const float* scales  = (const float*)d_in[2];  // (64,)
    const float* means   = (const float*)d_in[3];  // (100000,3)

    char* ws = (char*)d_ws;
    float* xs       = (float*)(ws + WS_XS_OFF);
    float* ys       = (float*)(ws + WS_YS_OFF);
    float* zs       = (float*)(ws + WS_ZS_OFF);
    float* ms       = (float*)(ws + WS_MS_OFF);
    float* partial  = (float*)(ws + WS_PARTIAL_OFF);
    float* partial2 = (float*)(ws + WS_PART2_OFF);
    float* out      = (float*)d_out;

    prep_kernel<<<(M + 255) / 256, 256, 0, stream>>>(means, xs, ys, zs, ms, out);
    nn_kernel<<<dim3(G, QS), 256, 0, stream>>>(outputs, c2ws, scales,
                                               xs, ys, zs, ms, partial);
    reduce1_kernel<<<dim3(16, HSEG), 256, 0, stream>>>(partial, partial2);
    reduce2_kernel<<<16, 256, 0, stream>>>(partial2, out);
}